// Round 1
// baseline (471.356 us; speedup 1.0000x reference)
//
#include <hip/hip_runtime.h>

// Problem constants (fixed by the reference setup)
#define N_ROWS   500000
#define NR1      25        // nr + 1
#define NGROUPS  20000     // N_ROWS / NR1
#define KCTX     20        // K context indices
#define H        128
#define NODES    10000
#define IDX_COLS 23        // 3 + K

// ---------------------------------------------------------------------------
// Kernel A: P[m] = x @ W1[:, m*128:(m+1)*128].T  for m = 0,1,2
//   P1[n][j] = sum_k x[n][k] * W1[j*384 + k]
//   P2[n][j] = sum_k x[n][k] * W1[j*384 + 128 + k]
//   P3[n][j] = sum_k x[n][k] * W1[j*384 + 256 + k]
// Block: 384 threads (6 waves), tile of TN nodes in LDS.
// ---------------------------------------------------------------------------
#define TN 16
__global__ __launch_bounds__(384) void k_precompute(
    const float* __restrict__ x, const float* __restrict__ W1,
    float* __restrict__ P) {
  __shared__ float xs[TN][H];
  const int nb = blockIdx.x * TN;
  const int t = threadIdx.x;
  for (int i = t; i < TN * H; i += 384) {
    xs[i >> 7][i & 127] = x[(size_t)(nb + (i >> 7)) * H + (i & 127)];
  }
  __syncthreads();
  const int m  = t >> 7;    // 0..2  -> which 128-col block of W1
  const int jj = t & 127;   // output column within block
  const float* __restrict__ wrow = W1 + (size_t)jj * (3 * H) + m * H;
  float acc[TN];
#pragma unroll
  for (int r = 0; r < TN; ++r) acc[r] = 0.f;
#pragma unroll 4
  for (int k = 0; k < H; ++k) {
    const float w = wrow[k];
#pragma unroll
    for (int r = 0; r < TN; ++r) acc[r] = fmaf(xs[r][k], w, acc[r]);
  }
  float* __restrict__ Pm = P + (size_t)m * NODES * H;
#pragma unroll
  for (int r = 0; r < TN; ++r) Pm[(size_t)(nb + r) * H + jj] = acc[r];
}

// ---------------------------------------------------------------------------
// Kernel B: per-group context term, folded with b1.
//   Cg[g][j] = b1[j] + (sum_{c<20} P3[idx_c][j]) / max(count(idx_c > 0), 1)
// One block (128 threads) per group; idx reads are wave-uniform (scalar).
// ---------------------------------------------------------------------------
__global__ __launch_bounds__(128) void k_context(
    const int* __restrict__ indices, const float* __restrict__ P3,
    const float* __restrict__ b1, float* __restrict__ Cg) {
  const int g = blockIdx.x;
  const int j = threadIdx.x;
  const int* __restrict__ row = indices + (size_t)g * NR1 * IDX_COLS + 3;
  float s = 0.f;
  int cnt = 0;
#pragma unroll
  for (int c = 0; c < KCTX; ++c) {
    const int idx = row[c];
    s += P3[(size_t)idx * H + j];
    cnt += (idx > 0) ? 1 : 0;
  }
  const float norm = (float)((cnt > 1) ? cnt : 1);
  Cg[(size_t)g * H + j] = b1[j] + s / norm;
}

// ---------------------------------------------------------------------------
// Kernel C: main fused MLP. One lane per row.
//   h  = relu(P1[i0] + P2[i1] + Cg[r/25])            (128 VGPRs)
//   h2 = relu(h @ W2.T + b2)                          (64 outputs, j-loop)
//   out= h2 @ W3.T + b3                               (folded into j-loop)
// W2/b2/W3 addresses are wave-uniform -> scalar loads; FMA is v_fmac v,s,v.
// ---------------------------------------------------------------------------
__global__ __launch_bounds__(256) void k_main(
    const int* __restrict__ indices,
    const float* __restrict__ P1, const float* __restrict__ P2,
    const float* __restrict__ Cg,
    const float* __restrict__ W2, const float* __restrict__ b2,
    const float* __restrict__ W3, const float* __restrict__ b3,
    float* __restrict__ out) {
  const int r = blockIdx.x * blockDim.x + threadIdx.x;
  if (r >= N_ROWS) return;
  const int i0 = indices[(size_t)r * IDX_COLS + 0];
  const int i1 = indices[(size_t)r * IDX_COLS + 1];
  const int g  = r / NR1;

  const float4* __restrict__ a = (const float4*)(P1 + (size_t)i0 * H);
  const float4* __restrict__ b = (const float4*)(P2 + (size_t)i1 * H);
  const float4* __restrict__ c = (const float4*)(Cg + (size_t)g * H);

  float h[H];
#pragma unroll
  for (int q = 0; q < H / 4; ++q) {
    const float4 va = a[q], vb = b[q], vc = c[q];
    h[4 * q + 0] = fmaxf(va.x + vb.x + vc.x, 0.f);
    h[4 * q + 1] = fmaxf(va.y + vb.y + vc.y, 0.f);
    h[4 * q + 2] = fmaxf(va.z + vb.z + vc.z, 0.f);
    h[4 * q + 3] = fmaxf(va.w + vb.w + vc.w, 0.f);
  }

  float o = b3[0];
  for (int j = 0; j < 64; ++j) {
    const float* __restrict__ w = W2 + (size_t)j * H;
    float acc = b2[j];
#pragma unroll
    for (int k = 0; k < H; ++k) acc = fmaf(h[k], w[k], acc);
    o = fmaf(fmaxf(acc, 0.f), W3[j], o);
  }
  out[r] = o;
}

// ---------------------------------------------------------------------------
extern "C" void kernel_launch(void* const* d_in, const int* in_sizes, int n_in,
                              void* d_out, int out_size, void* d_ws, size_t ws_size,
                              hipStream_t stream) {
  const int*   indices = (const int*)  d_in[0];
  // d_in[1] = nr (scalar, fixed at 24)
  const float* x  = (const float*)d_in[2];
  const float* W1 = (const float*)d_in[3];
  const float* b1 = (const float*)d_in[4];
  const float* W2 = (const float*)d_in[5];
  const float* b2 = (const float*)d_in[6];
  const float* W3 = (const float*)d_in[7];
  const float* b3 = (const float*)d_in[8];
  float* out = (float*)d_out;

  // Workspace layout (floats): P1 | P2 | P3 | Cg  = 3*10000*128 + 20000*128
  float* P  = (float*)d_ws;                    // P1,P2,P3 contiguous
  float* P1 = P;
  float* P2 = P + (size_t)NODES * H;
  float* P3 = P + (size_t)2 * NODES * H;
  float* Cg = P + (size_t)3 * NODES * H;       // 20000*128

  k_precompute<<<NODES / TN, 384, 0, stream>>>(x, W1, P);
  k_context<<<NGROUPS, 128, 0, stream>>>(indices, P3, b1, Cg);
  k_main<<<(N_ROWS + 255) / 256, 256, 0, stream>>>(indices, P1, P2, Cg,
                                                   W2, b2, W3, b3, out);
}

// Round 2
// 351.530 us; speedup vs baseline: 1.3409x; 1.3409x over previous
//
#include <hip/hip_runtime.h>

// Problem constants (fixed by the reference setup)
#define N_ROWS   500000
#define NR1      25        // nr + 1
#define NGROUPS  20000     // N_ROWS / NR1
#define KCTX     20        // K context indices
#define H        128
#define NODES    10000
#define IDX_COLS 23        // 3 + K

// ---------------------------------------------------------------------------
// Kernel A: P[m] = x @ W1[:, m*128:(m+1)*128].T  for m = 0,1,2
// ---------------------------------------------------------------------------
#define TN 16
__global__ __launch_bounds__(384) void k_precompute(
    const float* __restrict__ x, const float* __restrict__ W1,
    float* __restrict__ P) {
  __shared__ float xs[TN][H];
  const int nb = blockIdx.x * TN;
  const int t = threadIdx.x;
  for (int i = t; i < TN * H; i += 384) {
    xs[i >> 7][i & 127] = x[(size_t)(nb + (i >> 7)) * H + (i & 127)];
  }
  __syncthreads();
  const int m  = t >> 7;    // 0..2  -> which 128-col block of W1
  const int jj = t & 127;   // output column within block
  const float* __restrict__ wrow = W1 + (size_t)jj * (3 * H) + m * H;
  float acc[TN];
#pragma unroll
  for (int r = 0; r < TN; ++r) acc[r] = 0.f;
#pragma unroll 4
  for (int k = 0; k < H; ++k) {
    const float w = wrow[k];
#pragma unroll
    for (int r = 0; r < TN; ++r) acc[r] = fmaf(xs[r][k], w, acc[r]);
  }
  float* __restrict__ Pm = P + (size_t)m * NODES * H;
#pragma unroll
  for (int r = 0; r < TN; ++r) Pm[(size_t)(nb + r) * H + jj] = acc[r];
}

// ---------------------------------------------------------------------------
// Kernel B: per-group context term, folded with b1.
//   Cg[g][j] = b1[j] + (sum_{c<20} P3[idx_c][j]) / max(count(idx_c > 0), 1)
// ---------------------------------------------------------------------------
__global__ __launch_bounds__(128) void k_context(
    const int* __restrict__ indices, const float* __restrict__ P3,
    const float* __restrict__ b1, float* __restrict__ Cg) {
  const int g = blockIdx.x;
  const int j = threadIdx.x;
  const int* __restrict__ row = indices + (size_t)g * NR1 * IDX_COLS + 3;
  float s = 0.f;
  int cnt = 0;
#pragma unroll
  for (int c = 0; c < KCTX; ++c) {
    const int idx = row[c];
    s += P3[(size_t)idx * H + j];
    cnt += (idx > 0) ? 1 : 0;
  }
  const float norm = (float)((cnt > 1) ? cnt : 1);
  Cg[(size_t)g * H + j] = b1[j] + s / norm;
}

// ---------------------------------------------------------------------------
// Kernel T: W2T[k][j] = W2[j][k]  (128 x 64, so k-rows are contiguous)
// ---------------------------------------------------------------------------
__global__ __launch_bounds__(64) void k_transpose(
    const float* __restrict__ W2, float* __restrict__ W2T) {
  const int k = blockIdx.x;   // 0..127
  const int j = threadIdx.x;  // 0..63
  W2T[(size_t)k * 64 + j] = W2[(size_t)j * H + k];
}

// ---------------------------------------------------------------------------
// Kernel C: main fused MLP. One lane per row, k-streaming formulation:
//   live state = acc[64] (layer-2 accumulators), NOT h[128]  -> no spills.
//   For each k: h_k = relu(P1[i0][k]+P2[i1][k]+Cg[g][k]);
//               acc[j] += h_k * W2T[k][j]   (W2T row contiguous, uniform, L1-hot)
//   Epilogue:   out = b3 + sum_j relu(acc[j]+b2[j]) * W3[j]
// __launch_bounds__(256,3): cap at ~170 VGPR (3 waves/SIMD), prevents spill.
// ---------------------------------------------------------------------------
__global__ __launch_bounds__(256, 3) void k_main(
    const int* __restrict__ indices,
    const float* __restrict__ P1, const float* __restrict__ P2,
    const float* __restrict__ Cg,
    const float* __restrict__ W2T, const float* __restrict__ b2,
    const float* __restrict__ W3, const float* __restrict__ b3,
    float* __restrict__ out) {
  const int r = blockIdx.x * blockDim.x + threadIdx.x;
  if (r >= N_ROWS) return;
  const int i0 = indices[(size_t)r * IDX_COLS + 0];
  const int i1 = indices[(size_t)r * IDX_COLS + 1];
  const int g  = r / NR1;

  const float4* __restrict__ a = (const float4*)(P1 + (size_t)i0 * H);
  const float4* __restrict__ b = (const float4*)(P2 + (size_t)i1 * H);
  const float4* __restrict__ c = (const float4*)(Cg + (size_t)g * H);

  float acc[64];
#pragma unroll
  for (int j = 0; j < 64; ++j) acc[j] = 0.f;

  for (int q = 0; q < H / 4; ++q) {
    const float4 va = a[q], vb = b[q], vc = c[q];
    float h4[4];
    h4[0] = fmaxf(va.x + vb.x + vc.x, 0.f);
    h4[1] = fmaxf(va.y + vb.y + vc.y, 0.f);
    h4[2] = fmaxf(va.z + vb.z + vc.z, 0.f);
    h4[3] = fmaxf(va.w + vb.w + vc.w, 0.f);
#pragma unroll
    for (int kk = 0; kk < 4; ++kk) {
      const float4* __restrict__ wrow =
          (const float4*)(W2T + (size_t)(4 * q + kk) * 64);
      const float hk = h4[kk];
#pragma unroll
      for (int jq = 0; jq < 16; ++jq) {
        const float4 w = wrow[jq];
        acc[4 * jq + 0] = fmaf(hk, w.x, acc[4 * jq + 0]);
        acc[4 * jq + 1] = fmaf(hk, w.y, acc[4 * jq + 1]);
        acc[4 * jq + 2] = fmaf(hk, w.z, acc[4 * jq + 2]);
        acc[4 * jq + 3] = fmaf(hk, w.w, acc[4 * jq + 3]);
      }
    }
  }

  float o = b3[0];
#pragma unroll
  for (int j = 0; j < 64; ++j) {
    o = fmaf(fmaxf(acc[j] + b2[j], 0.f), W3[j], o);
  }
  out[r] = o;
}

// ---------------------------------------------------------------------------
extern "C" void kernel_launch(void* const* d_in, const int* in_sizes, int n_in,
                              void* d_out, int out_size, void* d_ws, size_t ws_size,
                              hipStream_t stream) {
  const int*   indices = (const int*)  d_in[0];
  // d_in[1] = nr (scalar, fixed at 24)
  const float* x  = (const float*)d_in[2];
  const float* W1 = (const float*)d_in[3];
  const float* b1 = (const float*)d_in[4];
  const float* W2 = (const float*)d_in[5];
  const float* b2 = (const float*)d_in[6];
  const float* W3 = (const float*)d_in[7];
  const float* b3 = (const float*)d_in[8];
  float* out = (float*)d_out;

  // Workspace layout (floats): P1 | P2 | P3 | Cg | W2T
  float* P   = (float*)d_ws;
  float* P1  = P;
  float* P2  = P + (size_t)NODES * H;
  float* P3  = P + (size_t)2 * NODES * H;
  float* Cg  = P + (size_t)3 * NODES * H;            // 20000*128
  float* W2T = Cg + (size_t)NGROUPS * H;             // 128*64

  k_transpose<<<H, 64, 0, stream>>>(W2, W2T);
  k_precompute<<<NODES / TN, 384, 0, stream>>>(x, W1, P);
  k_context<<<NGROUPS, 128, 0, stream>>>(indices, P3, b1, Cg);
  k_main<<<(N_ROWS + 255) / 256, 256, 0, stream>>>(indices, P1, P2, Cg,
                                                   W2T, b2, W3, b3, out);
}

// Round 3
// 319.796 us; speedup vs baseline: 1.4739x; 1.0992x over previous
//
#include <hip/hip_runtime.h>

// Problem constants (fixed by the reference setup)
#define N_ROWS   500000
#define NR1      25        // nr + 1
#define NGROUPS  20000     // N_ROWS / NR1
#define KCTX     20        // K context indices
#define H        128
#define NODES    10000
#define IDX_COLS 23        // 3 + K

// ---------------------------------------------------------------------------
// Kernel A: P[m] = x @ W1[:, m*128:(m+1)*128].T  for m = 0,1,2
// ---------------------------------------------------------------------------
#define TN 16
__global__ __launch_bounds__(384) void k_precompute(
    const float* __restrict__ x, const float* __restrict__ W1,
    float* __restrict__ P) {
  __shared__ float xs[TN][H];
  const int nb = blockIdx.x * TN;
  const int t = threadIdx.x;
  for (int i = t; i < TN * H; i += 384) {
    xs[i >> 7][i & 127] = x[(size_t)(nb + (i >> 7)) * H + (i & 127)];
  }
  __syncthreads();
  const int m  = t >> 7;    // 0..2  -> which 128-col block of W1
  const int jj = t & 127;   // output column within block
  const float* __restrict__ wrow = W1 + (size_t)jj * (3 * H) + m * H;
  float acc[TN];
#pragma unroll
  for (int r = 0; r < TN; ++r) acc[r] = 0.f;
#pragma unroll 4
  for (int k = 0; k < H; ++k) {
    const float w = wrow[k];
#pragma unroll
    for (int r = 0; r < TN; ++r) acc[r] = fmaf(xs[r][k], w, acc[r]);
  }
  float* __restrict__ Pm = P + (size_t)m * NODES * H;
#pragma unroll
  for (int r = 0; r < TN; ++r) Pm[(size_t)(nb + r) * H + jj] = acc[r];
}

// ---------------------------------------------------------------------------
// Kernel C: fully fused main kernel. Block = 256 threads, 256 rows.
//  Phase 0a: stage W2^T into LDS (w2s[k][j], 32 KB).
//  Phase 0b: compute the <=12 context-group rows this block touches into
//            LDS (cgs[g][k] = b1[k] + mean of P3[ctx]), absorbing k_context.
//  Phase 1:  lane = (rowlane = tid>>2, jq = tid&3). Each lane: 4 rows
//            (q*64+rowlane) x 16 j-columns (jq*16..+16). acc[4][16] = 64
//            VGPRs. k-stream: h_k = relu(P1[i0][k]+P2[i1][k]+cgs[g][k]),
//            acc[q][jj] += h_k * w2s[k][j]. LDS reads are 2-way-bank (free)
//            and mostly broadcast; they overlap the VALU pipe.
//  Epilogue: p = sum_j relu(acc+b2)*W3 over own 16 j; __shfl_xor over the
//            4 j-quarters; lane jq==0 writes.
// ---------------------------------------------------------------------------
__global__ __launch_bounds__(256, 3) void k_main(
    const int* __restrict__ indices,
    const float* __restrict__ P1, const float* __restrict__ P2,
    const float* __restrict__ P3,
    const float* __restrict__ W2, const float* __restrict__ b1,
    const float* __restrict__ b2, const float* __restrict__ W3,
    const float* __restrict__ b3, float* __restrict__ out) {
  __shared__ float w2s[H][64];   // 32 KB  w2s[k][j] = W2[j][k]
  __shared__ float cgs[12][H];   // 6 KB   context rows (incl. b1)

  const int tid   = threadIdx.x;
  const int rbase = blockIdx.x * 256;

  // ---- phase 0a: W2 -> LDS transposed ----
  {
    const int j   = tid & 63;
    const int kc4 = tid >> 6;  // 0..3
    const float4* __restrict__ wrow = (const float4*)(W2 + (size_t)j * H);
#pragma unroll
    for (int c = 0; c < 8; ++c) {
      const int k0 = kc4 * 32 + c * 4;
      const float4 v = wrow[k0 >> 2];
      w2s[k0 + 0][j] = v.x;
      w2s[k0 + 1][j] = v.y;
      w2s[k0 + 2][j] = v.z;
      w2s[k0 + 3][j] = v.w;
    }
  }

  // ---- phase 0b: context groups for this block ----
  const int gbase = rbase / NR1;
  int rlast = rbase + 255; if (rlast > N_ROWS - 1) rlast = N_ROWS - 1;
  const int G = rlast / NR1 - gbase + 1;  // <= 12
  {
    const int j = tid & 127;
#pragma unroll
    for (int it = 0; it < 6; ++it) {
      const int gi = it * 2 + (tid >> 7);
      if (gi < G) {
        const int* __restrict__ rowidx =
            indices + (size_t)(gbase + gi) * NR1 * IDX_COLS + 3;
        float s = 0.f; int cnt = 0;
#pragma unroll
        for (int c = 0; c < KCTX; ++c) {
          const int idx = rowidx[c];
          s += P3[(size_t)idx * H + j];
          cnt += (idx > 0) ? 1 : 0;
        }
        const float norm = (float)((cnt > 1) ? cnt : 1);
        cgs[gi][j] = b1[j] + s / norm;
      }
    }
  }
  __syncthreads();

  // ---- phase 1: main k-stream ----
  const int rowlane = tid >> 2;  // 0..63
  const int jq      = tid & 3;   // j-quarter

  int rows[4], glocal[4];
  const float4* pa[4];
  const float4* pb[4];
#pragma unroll
  for (int q = 0; q < 4; ++q) {
    const int r  = rbase + q * 64 + rowlane;
    rows[q] = r;
    const int rc = (r < N_ROWS) ? r : (N_ROWS - 1);
    const int2 ii = *(const int2*)(indices + (size_t)rc * IDX_COLS);
    pa[q] = (const float4*)(P1 + (size_t)ii.x * H);
    pb[q] = (const float4*)(P2 + (size_t)ii.y * H);
    glocal[q] = rc / NR1 - gbase;
  }

  float acc[4][16];
#pragma unroll
  for (int q = 0; q < 4; ++q)
#pragma unroll
    for (int jj = 0; jj < 16; ++jj) acc[q][jj] = 0.f;

  for (int kc = 0; kc < 32; ++kc) {
    float h[4][4];
#pragma unroll
    for (int q = 0; q < 4; ++q) {
      const float4 va = pa[q][kc];
      const float4 vb = pb[q][kc];
      const float4 vc = *(const float4*)&cgs[glocal[q]][kc * 4];
      h[q][0] = fmaxf(va.x + vb.x + vc.x, 0.f);
      h[q][1] = fmaxf(va.y + vb.y + vc.y, 0.f);
      h[q][2] = fmaxf(va.z + vb.z + vc.z, 0.f);
      h[q][3] = fmaxf(va.w + vb.w + vc.w, 0.f);
    }
#pragma unroll
    for (int i = 0; i < 4; ++i) {
      float wv[16];
      const float4* __restrict__ wr = (const float4*)&w2s[kc * 4 + i][jq * 16];
      *(float4*)&wv[0]  = wr[0];
      *(float4*)&wv[4]  = wr[1];
      *(float4*)&wv[8]  = wr[2];
      *(float4*)&wv[12] = wr[3];
#pragma unroll
      for (int q = 0; q < 4; ++q) {
        const float hv = h[q][i];
#pragma unroll
        for (int jj = 0; jj < 16; ++jj)
          acc[q][jj] = fmaf(hv, wv[jj], acc[q][jj]);
      }
    }
  }

  // ---- epilogue: layer 3 + j-quarter reduction ----
  float b2v[16], w3v[16];
  {
    const float4* b2p = (const float4*)(b2 + jq * 16);
    const float4* w3p = (const float4*)(W3 + jq * 16);
    *(float4*)&b2v[0]  = b2p[0]; *(float4*)&b2v[4]  = b2p[1];
    *(float4*)&b2v[8]  = b2p[2]; *(float4*)&b2v[12] = b2p[3];
    *(float4*)&w3v[0]  = w3p[0]; *(float4*)&w3v[4]  = w3p[1];
    *(float4*)&w3v[8]  = w3p[2]; *(float4*)&w3v[12] = w3p[3];
  }
  const float bias3 = b3[0];
#pragma unroll
  for (int q = 0; q < 4; ++q) {
    float p = 0.f;
#pragma unroll
    for (int jj = 0; jj < 16; ++jj)
      p += fmaxf(acc[q][jj] + b2v[jj], 0.f) * w3v[jj];
    p += __shfl_xor(p, 1);
    p += __shfl_xor(p, 2);
    if (jq == 0 && rows[q] < N_ROWS) out[rows[q]] = p + bias3;
  }
}

// ---------------------------------------------------------------------------
extern "C" void kernel_launch(void* const* d_in, const int* in_sizes, int n_in,
                              void* d_out, int out_size, void* d_ws, size_t ws_size,
                              hipStream_t stream) {
  const int*   indices = (const int*)  d_in[0];
  // d_in[1] = nr (scalar, fixed at 24)
  const float* x  = (const float*)d_in[2];
  const float* W1 = (const float*)d_in[3];
  const float* b1 = (const float*)d_in[4];
  const float* W2 = (const float*)d_in[5];
  const float* b2 = (const float*)d_in[6];
  const float* W3 = (const float*)d_in[7];
  const float* b3 = (const float*)d_in[8];
  float* out = (float*)d_out;

  // Workspace layout (floats): P1 | P2 | P3
  float* P  = (float*)d_ws;
  float* P1 = P;
  float* P2 = P + (size_t)NODES * H;
  float* P3 = P + (size_t)2 * NODES * H;

  k_precompute<<<NODES / TN, 384, 0, stream>>>(x, W1, P);
  k_main<<<(N_ROWS + 255) / 256, 256, 0, stream>>>(indices, P1, P2, P3,
                                                   W2, b1, b2, W3, b3, out);
}

// Round 4
// 223.656 us; speedup vs baseline: 2.1075x; 1.4299x over previous
//
#include <hip/hip_runtime.h>
#include <hip/hip_bf16.h>

// Problem constants (fixed by the reference setup)
#define N_ROWS   500000
#define NR1      25        // nr + 1
#define NGROUPS  20000     // N_ROWS / NR1
#define KCTX     20        // K context indices
#define H        128
#define NODES    10000
#define IDX_COLS 23        // 3 + K

typedef __attribute__((ext_vector_type(8))) short short8;   // 8 bf16 = 4 VGPRs
typedef __attribute__((ext_vector_type(4))) float f32x4;    // MFMA C/D

// pack two floats -> two bf16 (RNE) as a 32-bit word
__device__ __forceinline__ unsigned pkbf(float lo, float hi) {
  __hip_bfloat162 h = __float22bfloat162_rn(make_float2(lo, hi));
  union { __hip_bfloat162 h; unsigned u; } c; c.h = h;
  return c.u;
}

// ---------------------------------------------------------------------------
// Kernel A: P[m] = x @ W1[:, m*128:(m+1)*128].T  for m = 0,1,2  (fp32)
// No LDS: x-tile addresses are wave-uniform -> scalar loads (SMEM pipe);
// W1 read as float4 per lane. TN=8 -> 1250 blocks for better balance.
// ---------------------------------------------------------------------------
#define TNODES 8
__global__ __launch_bounds__(384) void k_precompute(
    const float* __restrict__ x, const float* __restrict__ W1,
    float* __restrict__ P) {
  const int nb = blockIdx.x * TNODES;
  const int t  = threadIdx.x;
  const int m  = t >> 7;    // 0..2
  const int jj = t & 127;   // output column
  const float4* __restrict__ wrow = (const float4*)(W1 + (size_t)jj * (3 * H) + m * H);
  const float4* __restrict__ xr   = (const float4*)(x + (size_t)nb * H);

  float acc[TNODES];
#pragma unroll
  for (int r = 0; r < TNODES; ++r) acc[r] = 0.f;

#pragma unroll 4
  for (int k4 = 0; k4 < 32; ++k4) {
    const float4 w = wrow[k4];
#pragma unroll
    for (int r = 0; r < TNODES; ++r) {
      const float4 xv = xr[r * 32 + k4];   // wave-uniform -> s_load
      acc[r] = fmaf(xv.x, w.x, acc[r]);
      acc[r] = fmaf(xv.y, w.y, acc[r]);
      acc[r] = fmaf(xv.z, w.z, acc[r]);
      acc[r] = fmaf(xv.w, w.w, acc[r]);
    }
  }
  float* __restrict__ Pm = P + (size_t)m * NODES * H;
#pragma unroll
  for (int r = 0; r < TNODES; ++r) Pm[(size_t)(nb + r) * H + jj] = acc[r];
}

// ---------------------------------------------------------------------------
// Kernel C: fused main kernel, MFMA layer 2.
// Block = 256 threads (4 waves), 128 rows; wave w owns rows [w*32, w*32+32).
//  Phase 0a: W2 -> LDS as bf16, layout w2s[n][k] (n-stride 136 -> 2-way banks)
//  Phase 0b: <=7 context-group rows -> cgs LDS (b1 folded, /norm applied)
//  Phase 1:  A-fragments built IN REGISTERS: lane(m=lane&15, quad=lane>>4)
//            holds h[row=rt*16+m][k=kt*32+quad*8 .. +8] = relu(P1[i0]+P2[i1]+cg)
//            rounded to bf16. Each P byte read exactly once per block.
//  Phase 2:  16x16x32 bf16 MFMA: acc[rt][ct] over 4 K-tiles.
//  Epilogue: s = sum_ct relu(acc+b2)*W3, shfl_xor-reduce over 16 cols, write.
// ---------------------------------------------------------------------------
__global__ __launch_bounds__(256, 3) void k_main(
    const int* __restrict__ indices,
    const float* __restrict__ P1, const float* __restrict__ P2,
    const float* __restrict__ P3,
    const float* __restrict__ W2, const float* __restrict__ b1,
    const float* __restrict__ b2, const float* __restrict__ W3,
    const float* __restrict__ b3, float* __restrict__ out) {
  __shared__ short w2s[64][136];   // bf16 W2[n][k], padded: 17.4 KB
  __shared__ float cgs[7][132];    // context rows (b1 folded), padded: 3.7 KB

  const int tid   = threadIdx.x;
  const int rbase = blockIdx.x * 128;

  // ---- phase 0a: W2 -> LDS bf16 ----
  for (int idx = tid; idx < 64 * 64; idx += 256) {
    const int n  = idx >> 6;        // row 0..63
    const int kp = idx & 63;        // k-pair 0..63
    const float2 w = *(const float2*)(W2 + (size_t)n * H + kp * 2);
    *(unsigned*)&w2s[n][kp * 2] = pkbf(w.x, w.y);
  }

  // ---- phase 0b: context groups for this block ----
  const int gbase = rbase / NR1;
  {
    int rlast = rbase + 127; if (rlast > N_ROWS - 1) rlast = N_ROWS - 1;
    const int G   = rlast / NR1 - gbase + 1;   // <= 7
    const int j   = tid & 127;
    const int sub = tid >> 7;
#pragma unroll
    for (int it = 0; it < 4; ++it) {
      const int gi = it * 2 + sub;
      if (gi < G) {
        const int* __restrict__ rowidx =
            indices + (size_t)(gbase + gi) * NR1 * IDX_COLS + 3;
        float s = 0.f; int cnt = 0;
#pragma unroll
        for (int c = 0; c < KCTX; ++c) {
          const int idx = rowidx[c];
          s += P3[(size_t)idx * H + j];
          cnt += (idx > 0) ? 1 : 0;
        }
        const float norm = (float)((cnt > 1) ? cnt : 1);
        cgs[gi][j] = b1[j] + s / norm;
      }
    }
  }
  __syncthreads();

  // ---- phase 1: A-fragments in registers ----
  const int lane = tid & 63;
  const int wv   = tid >> 6;
  const int col  = lane & 15;
  const int quad = lane >> 4;
  const int Rw   = rbase + wv * 32;

  int gl[2];
  const float4* pa[2];
  const float4* pb[2];
#pragma unroll
  for (int rt = 0; rt < 2; ++rt) {
    const int r  = Rw + rt * 16 + col;
    const int rc = (r < N_ROWS) ? r : (N_ROWS - 1);
    const int i0 = indices[(size_t)rc * IDX_COLS + 0];
    const int i1 = indices[(size_t)rc * IDX_COLS + 1];
    pa[rt] = (const float4*)(P1 + (size_t)i0 * H);
    pb[rt] = (const float4*)(P2 + (size_t)i1 * H);
    gl[rt] = rc / NR1 - gbase;
  }

  short8 A[2][4];
#pragma unroll
  for (int rt = 0; rt < 2; ++rt) {
#pragma unroll
    for (int kt = 0; kt < 4; ++kt) {
      const int f4 = kt * 8 + quad * 2;     // float4 index of k-window
      const float4 a0 = pa[rt][f4], a1 = pa[rt][f4 + 1];
      const float4 p0 = pb[rt][f4], p1 = pb[rt][f4 + 1];
      const float4 c0 = *(const float4*)&cgs[gl[rt]][kt * 32 + quad * 8];
      const float4 c1 = *(const float4*)&cgs[gl[rt]][kt * 32 + quad * 8 + 4];
      const float h0 = fmaxf(a0.x + p0.x + c0.x, 0.f);
      const float h1 = fmaxf(a0.y + p0.y + c0.y, 0.f);
      const float h2 = fmaxf(a0.z + p0.z + c0.z, 0.f);
      const float h3 = fmaxf(a0.w + p0.w + c0.w, 0.f);
      const float h4 = fmaxf(a1.x + p1.x + c1.x, 0.f);
      const float h5 = fmaxf(a1.y + p1.y + c1.y, 0.f);
      const float h6 = fmaxf(a1.z + p1.z + c1.z, 0.f);
      const float h7 = fmaxf(a1.w + p1.w + c1.w, 0.f);
      union { short8 v; unsigned u[4]; } pk;
      pk.u[0] = pkbf(h0, h1);
      pk.u[1] = pkbf(h2, h3);
      pk.u[2] = pkbf(h4, h5);
      pk.u[3] = pkbf(h6, h7);
      A[rt][kt] = pk.v;
    }
  }

  // ---- phase 2: MFMA ----
  f32x4 acc[2][4];
#pragma unroll
  for (int rt = 0; rt < 2; ++rt)
#pragma unroll
    for (int ct = 0; ct < 4; ++ct) acc[rt][ct] = (f32x4)(0.f);

#pragma unroll
  for (int kt = 0; kt < 4; ++kt) {
#pragma unroll
    for (int ct = 0; ct < 4; ++ct) {
      const short8 Bf = *(const short8*)&w2s[ct * 16 + col][kt * 32 + quad * 8];
#pragma unroll
      for (int rt = 0; rt < 2; ++rt)
        acc[rt][ct] = __builtin_amdgcn_mfma_f32_16x16x32_bf16(
            A[rt][kt], Bf, acc[rt][ct], 0, 0, 0);
    }
  }

  // ---- epilogue: layer 3 + column reduction ----
  float b2v[4], w3v[4];
#pragma unroll
  for (int ct = 0; ct < 4; ++ct) {
    b2v[ct] = b2[ct * 16 + col];
    w3v[ct] = W3[ct * 16 + col];
  }
  const float bias3 = b3[0];
#pragma unroll
  for (int rt = 0; rt < 2; ++rt) {
#pragma unroll
    for (int reg = 0; reg < 4; ++reg) {
      float s = 0.f;
#pragma unroll
      for (int ct = 0; ct < 4; ++ct)
        s += fmaxf(acc[rt][ct][reg] + b2v[ct], 0.f) * w3v[ct];
      s += __shfl_xor(s, 1);
      s += __shfl_xor(s, 2);
      s += __shfl_xor(s, 4);
      s += __shfl_xor(s, 8);
      if (col == 0) {
        const int row = Rw + rt * 16 + quad * 4 + reg;   // C row = quad*4+reg
        if (row < N_ROWS) out[row] = s + bias3;
      }
    }
  }
}

// ---------------------------------------------------------------------------
extern "C" void kernel_launch(void* const* d_in, const int* in_sizes, int n_in,
                              void* d_out, int out_size, void* d_ws, size_t ws_size,
                              hipStream_t stream) {
  const int*   indices = (const int*)  d_in[0];
  // d_in[1] = nr (scalar, fixed at 24)
  const float* x  = (const float*)d_in[2];
  const float* W1 = (const float*)d_in[3];
  const float* b1 = (const float*)d_in[4];
  const float* W2 = (const float*)d_in[5];
  const float* b2 = (const float*)d_in[6];
  const float* W3 = (const float*)d_in[7];
  const float* b3 = (const float*)d_in[8];
  float* out = (float*)d_out;

  // Workspace layout (floats): P1 | P2 | P3
  float* P  = (float*)d_ws;
  float* P1 = P;
  float* P2 = P + (size_t)NODES * H;
  float* P3 = P + (size_t)2 * NODES * H;

  k_precompute<<<NODES / TNODES, 384, 0, stream>>>(x, W1, P);
  k_main<<<(N_ROWS + 127) / 128, 256, 0, stream>>>(indices, P1, P2, P3,
                                                   W2, b1, b2, W3, b3, out);
}

// Round 5
// 169.025 us; speedup vs baseline: 2.7887x; 1.3232x over previous
//
#include <hip/hip_runtime.h>
#include <hip/hip_bf16.h>

// Problem constants (fixed by the reference setup)
#define N_ROWS   500000
#define NR1      25        // nr + 1
#define NGROUPS  20000     // N_ROWS / NR1
#define KCTX     20        // K context indices
#define H        128
#define NODES    10000
#define IDX_COLS 23        // 3 + K

typedef __attribute__((ext_vector_type(8))) short short8;   // 8 bf16 = 4 VGPRs
typedef __attribute__((ext_vector_type(4))) float f32x4;    // MFMA C/D

// pack two floats -> two bf16 (RNE) as a 32-bit word
__device__ __forceinline__ unsigned pkbf(float lo, float hi) {
  __hip_bfloat162 h = __float22bfloat162_rn(make_float2(lo, hi));
  union { __hip_bfloat162 h; unsigned u; } c; c.h = h;
  return c.u;
}
__device__ __forceinline__ float bf2f(unsigned short u) {
  union { unsigned u; float f; } c; c.u = ((unsigned)u) << 16; return c.f;
}

// ---------------------------------------------------------------------------
// Kernel P: pack (i0,i1) per row into a contiguous int2 array.
// ---------------------------------------------------------------------------
__global__ __launch_bounds__(256) void k_pack(
    const int* __restrict__ indices, int2* __restrict__ idx2) {
  const int r = blockIdx.x * 256 + threadIdx.x;
  if (r < N_ROWS) {
    idx2[r] = make_int2(indices[(size_t)r * IDX_COLS + 0],
                        indices[(size_t)r * IDX_COLS + 1]);
  }
}

// ---------------------------------------------------------------------------
// Kernel A (v3): P[m] = x @ W1m.T via split-bf16 MFMA, output stored as bf16.
//   x = x_hi + x_lo, W = w_hi + w_lo (bf16 each); P ~= xh*wh + xl*wh + xh*wl
//   (dropped lo*lo term is ~2^-18 relative — fp32-equivalent accuracy).
// Grid: (ceil(10000/128), 3).  Block: 256 thr / 4 waves; wave owns 32 nodes.
// LDS: W1m as bf16 hi/lo, [j][k] with k-stride 132 (bank spread).
// ---------------------------------------------------------------------------
__global__ __launch_bounds__(256) void k_precompute(
    const float* __restrict__ x, const float* __restrict__ W1,
    unsigned short* __restrict__ Pb) {
  __shared__ short w_hi[128][132];   // 33.8 KB
  __shared__ short w_lo[128][132];   // 33.8 KB

  const int tid   = threadIdx.x;
  const int m     = blockIdx.y;            // 0..2
  const int tbase = blockIdx.x * 128;      // node tile base

  // ---- stage W1m -> LDS as bf16 hi/lo (coalesced float4 reads) ----
  for (int it = 0; it < 16; ++it) {
    const int f  = it * 256 + tid;         // 0..4095 float4s (128 j x 32)
    const int j  = f >> 5;
    const int q4 = f & 31;
    const float4 v = *(const float4*)(W1 + (size_t)j * (3 * H) + m * H + q4 * 4);
    const unsigned h01 = pkbf(v.x, v.y);
    const unsigned h23 = pkbf(v.z, v.w);
    union { unsigned u; unsigned short s[2]; } a, b;
    a.u = h01; b.u = h23;
    const unsigned l01 = pkbf(v.x - bf2f(a.s[0]), v.y - bf2f(a.s[1]));
    const unsigned l23 = pkbf(v.z - bf2f(b.s[0]), v.w - bf2f(b.s[1]));
    *(unsigned*)&w_hi[j][q4 * 4]     = h01;
    *(unsigned*)&w_hi[j][q4 * 4 + 2] = h23;
    *(unsigned*)&w_lo[j][q4 * 4]     = l01;
    *(unsigned*)&w_lo[j][q4 * 4 + 2] = l23;
  }
  __syncthreads();

  const int lane = tid & 63;
  const int wv   = tid >> 6;
  const int col  = lane & 15;
  const int quad = lane >> 4;
  const int nwb  = tbase + wv * 32;        // wave node base (32 nodes)

  f32x4 acc[2][8];
#pragma unroll
  for (int rt = 0; rt < 2; ++rt)
#pragma unroll
    for (int ct = 0; ct < 8; ++ct) acc[rt][ct] = (f32x4)(0.f);

#pragma unroll
  for (int kt = 0; kt < 4; ++kt) {
    short8 Ah[2], Al[2];
#pragma unroll
    for (int rt = 0; rt < 2; ++rt) {
      int node = nwb + rt * 16 + col;
      if (node > NODES - 1) node = NODES - 1;
      const float4* xr = (const float4*)(x + (size_t)node * H);
      const int f4 = kt * 8 + quad * 2;
      const float4 v0 = xr[f4], v1 = xr[f4 + 1];
      union { short8 v; unsigned u[4]; unsigned short s[8]; } Hh, Ll;
      Hh.u[0] = pkbf(v0.x, v0.y);
      Hh.u[1] = pkbf(v0.z, v0.w);
      Hh.u[2] = pkbf(v1.x, v1.y);
      Hh.u[3] = pkbf(v1.z, v1.w);
      Ll.u[0] = pkbf(v0.x - bf2f(Hh.s[0]), v0.y - bf2f(Hh.s[1]));
      Ll.u[1] = pkbf(v0.z - bf2f(Hh.s[2]), v0.w - bf2f(Hh.s[3]));
      Ll.u[2] = pkbf(v1.x - bf2f(Hh.s[4]), v1.y - bf2f(Hh.s[5]));
      Ll.u[3] = pkbf(v1.z - bf2f(Hh.s[6]), v1.w - bf2f(Hh.s[7]));
      Ah[rt] = Hh.v; Al[rt] = Ll.v;
    }
#pragma unroll
    for (int ct = 0; ct < 8; ++ct) {
      const short8 Bh = *(const short8*)&w_hi[ct * 16 + col][kt * 32 + quad * 8];
      const short8 Bl = *(const short8*)&w_lo[ct * 16 + col][kt * 32 + quad * 8];
#pragma unroll
      for (int rt = 0; rt < 2; ++rt) {
        acc[rt][ct] = __builtin_amdgcn_mfma_f32_16x16x32_bf16(Ah[rt], Bh, acc[rt][ct], 0, 0, 0);
        acc[rt][ct] = __builtin_amdgcn_mfma_f32_16x16x32_bf16(Al[rt], Bh, acc[rt][ct], 0, 0, 0);
        acc[rt][ct] = __builtin_amdgcn_mfma_f32_16x16x32_bf16(Ah[rt], Bl, acc[rt][ct], 0, 0, 0);
      }
    }
  }

  // ---- write P[m] as bf16; C row = quad*4+reg, col = ct*16 + (lane&15) ----
  unsigned short* __restrict__ Pm = Pb + (size_t)m * NODES * H;
#pragma unroll
  for (int rt = 0; rt < 2; ++rt) {
#pragma unroll
    for (int reg = 0; reg < 4; ++reg) {
      const int node = nwb + rt * 16 + quad * 4 + reg;
      if (node < NODES) {
#pragma unroll
        for (int ct = 0; ct < 8; ++ct) {
          union { unsigned u; unsigned short s[2]; } c;
          c.u = pkbf(acc[rt][ct][reg], 0.f);
          Pm[(size_t)node * H + ct * 16 + col] = c.s[0];
        }
      }
    }
  }
}

// ---------------------------------------------------------------------------
// Kernel C: fused main kernel, MFMA layer 2, bf16 P gathers.
// Block = 256 threads (4 waves), 128 rows; wave w owns rows [w*32, +32).
// ---------------------------------------------------------------------------
__global__ __launch_bounds__(256) void k_main(
    const int* __restrict__ indices, const int2* __restrict__ idx2,
    const unsigned short* __restrict__ P1b, const unsigned short* __restrict__ P2b,
    const unsigned short* __restrict__ P3b,
    const float* __restrict__ W2, const float* __restrict__ b1,
    const float* __restrict__ b2, const float* __restrict__ W3,
    const float* __restrict__ b3, float* __restrict__ out) {
  __shared__ short w2s[64][136];   // bf16 W2[n][k], padded: 17.4 KB
  __shared__ float cgs[7][132];    // context rows (b1 folded), padded: 3.7 KB

  const int tid   = threadIdx.x;
  const int rbase = blockIdx.x * 128;

  // ---- phase 0a: W2 -> LDS bf16 ----
  for (int idx = tid; idx < 64 * 64; idx += 256) {
    const int n  = idx >> 6;        // row 0..63
    const int kp = idx & 63;        // k-pair 0..63
    const float2 w = *(const float2*)(W2 + (size_t)n * H + kp * 2);
    *(unsigned*)&w2s[n][kp * 2] = pkbf(w.x, w.y);
  }

  // ---- phase 0b: context groups for this block (bf16 P3 gathers) ----
  const int gbase = rbase / NR1;
  {
    int rlast = rbase + 127; if (rlast > N_ROWS - 1) rlast = N_ROWS - 1;
    const int G   = rlast / NR1 - gbase + 1;   // <= 7
    const int j   = tid & 127;
    const int sub = tid >> 7;
#pragma unroll
    for (int it = 0; it < 4; ++it) {
      const int gi = it * 2 + sub;
      if (gi < G) {
        const int* __restrict__ rowidx =
            indices + (size_t)(gbase + gi) * NR1 * IDX_COLS + 3;
        float s = 0.f; int cnt = 0;
#pragma unroll
        for (int c = 0; c < KCTX; ++c) {
          const int idx = rowidx[c];
          s += bf2f(P3b[(size_t)idx * H + j]);
          cnt += (idx > 0) ? 1 : 0;
        }
        const float norm = (float)((cnt > 1) ? cnt : 1);
        cgs[gi][j] = b1[j] + s / norm;
      }
    }
  }
  __syncthreads();

  // ---- phase 1: A-fragments in registers from bf16 gathers ----
  const int lane = tid & 63;
  const int wv   = tid >> 6;
  const int col  = lane & 15;
  const int quad = lane >> 4;
  const int Rw   = rbase + wv * 32;

  int gl[2];
  const short8* pa[2];
  const short8* pb[2];
#pragma unroll
  for (int rt = 0; rt < 2; ++rt) {
    const int r  = Rw + rt * 16 + col;
    const int rc = (r < N_ROWS) ? r : (N_ROWS - 1);
    const int2 ii = idx2[rc];
    pa[rt] = (const short8*)(P1b + (size_t)ii.x * H);
    pb[rt] = (const short8*)(P2b + (size_t)ii.y * H);
    gl[rt] = rc / NR1 - gbase;
  }

  short8 A[2][4];
#pragma unroll
  for (int rt = 0; rt < 2; ++rt) {
#pragma unroll
    for (int kt = 0; kt < 4; ++kt) {
      union { short8 v; unsigned short s[8]; } ua, ub;
      ua.v = pa[rt][kt * 4 + quad];
      ub.v = pb[rt][kt * 4 + quad];
      const float4 c0 = *(const float4*)&cgs[gl[rt]][kt * 32 + quad * 8];
      const float4 c1 = *(const float4*)&cgs[gl[rt]][kt * 32 + quad * 8 + 4];
      const float h0 = fmaxf(bf2f(ua.s[0]) + bf2f(ub.s[0]) + c0.x, 0.f);
      const float h1 = fmaxf(bf2f(ua.s[1]) + bf2f(ub.s[1]) + c0.y, 0.f);
      const float h2 = fmaxf(bf2f(ua.s[2]) + bf2f(ub.s[2]) + c0.z, 0.f);
      const float h3 = fmaxf(bf2f(ua.s[3]) + bf2f(ub.s[3]) + c0.w, 0.f);
      const float h4 = fmaxf(bf2f(ua.s[4]) + bf2f(ub.s[4]) + c1.x, 0.f);
      const float h5 = fmaxf(bf2f(ua.s[5]) + bf2f(ub.s[5]) + c1.y, 0.f);
      const float h6 = fmaxf(bf2f(ua.s[6]) + bf2f(ub.s[6]) + c1.z, 0.f);
      const float h7 = fmaxf(bf2f(ua.s[7]) + bf2f(ub.s[7]) + c1.w, 0.f);
      union { short8 v; unsigned u[4]; } pk;
      pk.u[0] = pkbf(h0, h1);
      pk.u[1] = pkbf(h2, h3);
      pk.u[2] = pkbf(h4, h5);
      pk.u[3] = pkbf(h6, h7);
      A[rt][kt] = pk.v;
    }
  }

  // ---- phase 2: MFMA ----
  f32x4 acc[2][4];
#pragma unroll
  for (int rt = 0; rt < 2; ++rt)
#pragma unroll
    for (int ct = 0; ct < 4; ++ct) acc[rt][ct] = (f32x4)(0.f);

#pragma unroll
  for (int kt = 0; kt < 4; ++kt) {
#pragma unroll
    for (int ct = 0; ct < 4; ++ct) {
      const short8 Bf = *(const short8*)&w2s[ct * 16 + col][kt * 32 + quad * 8];
#pragma unroll
      for (int rt = 0; rt < 2; ++rt)
        acc[rt][ct] = __builtin_amdgcn_mfma_f32_16x16x32_bf16(
            A[rt][kt], Bf, acc[rt][ct], 0, 0, 0);
    }
  }

  // ---- epilogue: layer 3 + column reduction ----
  float b2v[4], w3v[4];
#pragma unroll
  for (int ct = 0; ct < 4; ++ct) {
    b2v[ct] = b2[ct * 16 + col];
    w3v[ct] = W3[ct * 16 + col];
  }
  const float bias3 = b3[0];
#pragma unroll
  for (int rt = 0; rt < 2; ++rt) {
#pragma unroll
    for (int reg = 0; reg < 4; ++reg) {
      float s = 0.f;
#pragma unroll
      for (int ct = 0; ct < 4; ++ct)
        s += fmaxf(acc[rt][ct][reg] + b2v[ct], 0.f) * w3v[ct];
      s += __shfl_xor(s, 1);
      s += __shfl_xor(s, 2);
      s += __shfl_xor(s, 4);
      s += __shfl_xor(s, 8);
      if (col == 0) {
        const int row = Rw + rt * 16 + quad * 4 + reg;   // C row = quad*4+reg
        if (row < N_ROWS) out[row] = s + bias3;
      }
    }
  }
}

// ---------------------------------------------------------------------------
extern "C" void kernel_launch(void* const* d_in, const int* in_sizes, int n_in,
                              void* d_out, int out_size, void* d_ws, size_t ws_size,
                              hipStream_t stream) {
  const int*   indices = (const int*)  d_in[0];
  // d_in[1] = nr (scalar, fixed at 24)
  const float* x  = (const float*)d_in[2];
  const float* W1 = (const float*)d_in[3];
  const float* b1 = (const float*)d_in[4];
  const float* W2 = (const float*)d_in[5];
  const float* b2 = (const float*)d_in[6];
  const float* W3 = (const float*)d_in[7];
  const float* b3 = (const float*)d_in[8];
  float* out = (float*)d_out;

  // Workspace layout: Pb (bf16: 3*10000*128 = 7.68 MB) | idx2 (int2: 4 MB)
  unsigned short* Pb  = (unsigned short*)d_ws;
  unsigned short* P1b = Pb;
  unsigned short* P2b = Pb + (size_t)NODES * H;
  unsigned short* P3b = Pb + (size_t)2 * NODES * H;
  int2* idx2 = (int2*)((char*)d_ws + (size_t)3 * NODES * H * sizeof(unsigned short));

  k_pack<<<(N_ROWS + 255) / 256, 256, 0, stream>>>(indices, idx2);
  dim3 gpre((NODES + 127) / 128, 3);
  k_precompute<<<gpre, 256, 0, stream>>>(x, W1, Pb);
  k_main<<<(N_ROWS + 127) / 128, 256, 0, stream>>>(indices, idx2, P1b, P2b, P3b,
                                                   W2, b1, b2, W3, b3, out);
}